// Round 17
// baseline (11632.383 us; speedup 1.0000x reference)
//
#include <hip/hip_runtime.h>

// LSTM stack: B=64, T=256, N=M=1024, L=2 — 4-DOMAIN PIPELINE.
// 256 WGs (1/CU), 1024 threads. dom = cu&3, cuD = cu>>2 (0..63):
//   dom0: L0-serial (Wh0 in LDS; 16 m-units/CU). Serial chain: h0[t-1] -> h0[t].
//   dom1: L1-serial (Wh1). Chain: h1[t-1] -> h1[t]; writes out.
//   dom2: Bridge0 (Wx0): g0x[t] = Wx0*x[t] + b0, free-running (ring-throttled).
//   dom3: Bridge1 (Wx1): g1x[t] = Wx1*h0[t] + b1, gated on L0 progress.
// Serial CU: 4 busy waves (bt=w), each owns 16m x 16b for ALL 4 gates with
// full K=1024 in-wave -> NO LDS reduce, NO shuffles on the chain; pointwise is
// per-lane (i,f,g,o occupy the same lane across the 4 accs). Bridge CU: 16
// waves (rt,bt), one 16x16 tile each, K=1024.
// Rings (32 slots): h0,h1 [32][64][1024] bf16; g0x,g1x [32][64][4096] bf16.
// Per-domain leaf-tree barrier (8x8) + per-XCD release lines + prog counters;
// WT agent-atomic 8B data stores drained before arrival => prog>=t implies
// data at LLC. Per-(dom,XCD) leader L2-inv at ring wrap (k%32==31).
// Gates: L0 waits progB0>=k+2 & progB1>=k-30; L1 waits progB1>=k+2;
// B0 waits prog0>=k-30; B1 waits prog0>=k+2 & prog1>=k-30. No cycles.

#define T_STEPS 256
#define B_SZ 64
#define M_SZ 1024
#define N_SZ 1024
#define G4M 4096
#define BM 65536                        // B*M
#define RING 32
#define GSTRIDE ((size_t)262144)        // 64*4096 elems per gates-ring slot
#define OUTS ((size_t)16777216)         // B*T*M

typedef short short8 __attribute__((ext_vector_type(8)));
typedef float f32x4 __attribute__((ext_vector_type(4)));

static __device__ __forceinline__ unsigned short f2bf(float f) {
  union { float f; unsigned int u; } v; v.f = f;
  unsigned int u = v.u;
  unsigned int r = (u + 0x7FFFu + ((u >> 16) & 1u)) >> 16;
  return (unsigned short)r;
}
static __device__ __forceinline__ float bf2f(unsigned int us) {
  union { unsigned int u; float f; } v; v.u = (us & 0xFFFFu) << 16;
  return v.f;
}
static __device__ __forceinline__ float sigf(float x) {
  return 1.f / (1.f + __expf(-x));
}
static __device__ __forceinline__ float tanhfast(float x) {
  return 2.f / (1.f + __expf(-2.f * x)) - 1.f;
}
static __device__ __forceinline__ short8 ld16(const unsigned short* p) {
  return *reinterpret_cast<const short8*>(p);
}
static __device__ __forceinline__ void store_wt16(void* p, f32x4 v) {
  asm volatile("global_store_dwordx4 %0, %1, off sc0 sc1" :: "v"(p), "v"(v) : "memory");
}
static __device__ __forceinline__ int xcc_id() {
  int v;
  asm volatile("s_getreg_b32 %0, hwreg(HW_REG_XCC_ID)" : "=s"(v));
  return v & 7;
}

__global__ void convert_x_kernel(const float* __restrict__ x,
                                 unsigned short* __restrict__ xb, int n4) {
  int i = blockIdx.x * blockDim.x + threadIdx.x;
  int stride = gridDim.x * blockDim.x;
  for (; i < n4; i += stride) {
    float4 v = reinterpret_cast<const float4*>(x)[i];
    ushort4 o;
    o.x = f2bf(v.x); o.y = f2bf(v.y); o.z = f2bf(v.z); o.w = f2bf(v.w);
    reinterpret_cast<ushort4*>(xb)[i] = o;
  }
}

__global__ void init_h_kernel(const float* __restrict__ h,
                              unsigned short* __restrict__ h0r,
                              unsigned short* __restrict__ h1r) {
  int i = blockIdx.x * blockDim.x + threadIdx.x;  // 0..65535
  h0r[(size_t)(RING - 1) * BM + i] = f2bf(h[i]);
  h1r[(size_t)(RING - 1) * BM + i] = f2bf(h[BM + i]);
}

// bar 64B slots: leaf[dom*8+l] 0-31; root 32+dom; rel 36+dom*8+xcd;
// relB 68+dom*8+xcd; claim 100+dom*8+xcd; prog 132+dom.
__global__ __launch_bounds__(1024, 4) void lstm_pipeline(
    const unsigned short* __restrict__ xb,
    const float* __restrict__ c_in,
    const float* __restrict__ Wx,
    const float* __restrict__ Wh,
    const float* __restrict__ bias,
    float* __restrict__ out,
    unsigned short* __restrict__ h0r,
    unsigned short* __restrict__ h1r,
    unsigned short* __restrict__ g0x,
    unsigned short* __restrict__ g1x,
    int* bar) {
  __shared__ short8 sW[4][32][64];   // 128 KiB weights

  const int cu = blockIdx.x;
  const int tid = threadIdx.x;
  const int lane = tid & 63;
  const int w = tid >> 6;
  const int dom = cu & 3;
  const int cuD = cu >> 2;            // 0..63
  const int lay = dom & 1;
  const bool serial = (dom < 2);
  const int q = lane >> 4;            // 0..3
  const int bl = lane & 15;
  const int ko = q * 8;
  const int xcd = xcc_id();

  // ---- stage weights ----
  {
    const float* base = serial ? (Wh + (size_t)lay * G4M * M_SZ)
                               : (Wx + (size_t)lay * G4M * N_SZ);
#pragma unroll
    for (int idx4 = 0; idx4 < 4; ++idx4) {
      for (int s = tid; s < 32 * 64; s += 1024) {
        int kt = s >> 6, ls = s & 63, r = ls & 15;
        int k0 = kt * 32 + (ls >> 4) * 8;
        int j = serial ? (idx4 * 1024 + cuD * 16 + r)
                       : (cuD * 64 + idx4 * 16 + r);
        const float* sp = base + (size_t)j * 1024 + k0;
        float4 a = reinterpret_cast<const float4*>(sp)[0];
        float4 b2 = reinterpret_cast<const float4*>(sp)[1];
        short8 wv;
        wv[0] = (short)f2bf(a.x); wv[1] = (short)f2bf(a.y);
        wv[2] = (short)f2bf(a.z); wv[3] = (short)f2bf(a.w);
        wv[4] = (short)f2bf(b2.x); wv[5] = (short)f2bf(b2.y);
        wv[6] = (short)f2bf(b2.z); wv[7] = (short)f2bf(b2.w);
        sW[idx4][kt][ls] = wv;
      }
    }
  }

  // ---- per-(dom,XCD) leader election ----
  bool leader = false;
  if (tid == 0) {
    int expected = 0;
    leader = __hip_atomic_compare_exchange_strong(
        bar + 16 * (100 + dom * 8 + xcd), &expected, cu + 1, __ATOMIC_RELAXED,
        __ATOMIC_RELAXED, __HIP_MEMORY_SCOPE_AGENT);
  }
  __syncthreads();

  int* prog0  = bar + 16 * 132;
  int* prog1  = bar + 16 * 133;
  int* progB0 = bar + 16 * 134;
  int* progB1 = bar + 16 * 135;

  // ---- startup gates ----
  if (tid == 0) {
    int guard = 0;
    if (dom == 0) {
      while (__hip_atomic_load(progB0, __ATOMIC_RELAXED, __HIP_MEMORY_SCOPE_AGENT) < 1) {
        __builtin_amdgcn_s_sleep(1); if (++guard > (1 << 22)) break;
      }
    } else if (dom == 1) {
      while (__hip_atomic_load(progB1, __ATOMIC_RELAXED, __HIP_MEMORY_SCOPE_AGENT) < 1) {
        __builtin_amdgcn_s_sleep(1); if (++guard > (1 << 22)) break;
      }
    } else if (dom == 3) {
      while (__hip_atomic_load(prog0, __ATOMIC_RELAXED, __HIP_MEMORY_SCOPE_AGENT) < 1) {
        __builtin_amdgcn_s_sleep(1); if (++guard > (1 << 22)) break;
      }
    }
  }
  __syncthreads();

  int* myleaf = bar + 16 * (dom * 8 + (cuD & 7));
  int* myroot = bar + 16 * (32 + dom);
  int* myprog = bar + 16 * (132 + dom);
  int* rel  = bar + 16 * (36 + dom * 8 + xcd);
  int* relB = bar + 16 * (68 + dom * 8 + xcd);

  if (serial) {
    // ================= SERIAL DOMAIN (Wh only) =================
    unsigned short* hr = lay ? h1r : h0r;
    unsigned short* gr = lay ? g1x : g0x;
    const int bt = w & 3;                 // valid for w<4
    const int bg = bt * 16 + bl;
    const int mloc = cuD * 16 + q * 4;    // lane's first m
    float c_st[4] = {0.f, 0.f, 0.f, 0.f};
    if (w < 4) {
#pragma unroll
      for (int e = 0; e < 4; ++e)
        c_st[e] = c_in[lay * BM + bg * M_SZ + mloc + e];
    }

    for (int k = 0; k < T_STEPS; ++k) {
      const int rs = (k + RING - 1) & (RING - 1);
      const int wsl = k & (RING - 1);
      if (w < 4) {
        const unsigned short* hp = hr + (size_t)rs * BM + (size_t)bg * M_SZ;
        short8 f[32];
#pragma unroll
        for (int j = 0; j < 32; ++j) f[j] = ld16(hp + j * 32 + ko);
        asm volatile("" ::
          "v"(f[0]), "v"(f[1]), "v"(f[2]), "v"(f[3]), "v"(f[4]), "v"(f[5]),
          "v"(f[6]), "v"(f[7]), "v"(f[8]), "v"(f[9]), "v"(f[10]), "v"(f[11]),
          "v"(f[12]), "v"(f[13]), "v"(f[14]), "v"(f[15]));
        asm volatile("" ::
          "v"(f[16]), "v"(f[17]), "v"(f[18]), "v"(f[19]), "v"(f[20]), "v"(f[21]),
          "v"(f[22]), "v"(f[23]), "v"(f[24]), "v"(f[25]), "v"(f[26]), "v"(f[27]),
          "v"(f[28]), "v"(f[29]), "v"(f[30]), "v"(f[31]));
        // precomputed x-gates (bf16, 4 gates x ushort4)
        const unsigned short* gp = gr + (size_t)wsl * GSTRIDE + (size_t)bg * G4M + mloc;
        unsigned long long gv0 = *(const unsigned long long*)(gp);
        unsigned long long gv1 = *(const unsigned long long*)(gp + 1024);
        unsigned long long gv2 = *(const unsigned long long*)(gp + 2048);
        unsigned long long gv3 = *(const unsigned long long*)(gp + 3072);
        __builtin_amdgcn_sched_barrier(0);
        f32x4 a0 = {0.f,0.f,0.f,0.f}, a1 = {0.f,0.f,0.f,0.f};
        f32x4 a2 = {0.f,0.f,0.f,0.f}, a3 = {0.f,0.f,0.f,0.f};
#pragma unroll
        for (int j = 0; j < 32; ++j) {
          a0 = __builtin_amdgcn_mfma_f32_16x16x32_bf16(sW[0][j][lane], f[j], a0, 0, 0, 0);
          a1 = __builtin_amdgcn_mfma_f32_16x16x32_bf16(sW[1][j][lane], f[j], a1, 0, 0, 0);
          a2 = __builtin_amdgcn_mfma_f32_16x16x32_bf16(sW[2][j][lane], f[j], a2, 0, 0, 0);
          a3 = __builtin_amdgcn_mfma_f32_16x16x32_bf16(sW[3][j][lane], f[j], a3, 0, 0, 0);
        }
        float hv[4];
#pragma unroll
        for (int e = 0; e < 4; ++e) {
          float ig = a0[e] + bf2f((unsigned int)(gv0 >> (16 * e)));
          float fg = a1[e] + bf2f((unsigned int)(gv1 >> (16 * e)));
          float gg = a2[e] + bf2f((unsigned int)(gv2 >> (16 * e)));
          float og = a3[e] + bf2f((unsigned int)(gv3 >> (16 * e)));
          float c = sigf(fg) * c_st[e] + sigf(ig) * tanhfast(gg);
          c_st[e] = c;
          hv[e] = sigf(og) * tanhfast(c);
        }
        unsigned long long hb =
            (unsigned long long)f2bf(hv[0]) |
            ((unsigned long long)f2bf(hv[1]) << 16) |
            ((unsigned long long)f2bf(hv[2]) << 32) |
            ((unsigned long long)f2bf(hv[3]) << 48);
        __hip_atomic_store(
            (unsigned long long*)(hr + (size_t)wsl * BM + (size_t)bg * M_SZ + mloc),
            hb, __ATOMIC_RELAXED, __HIP_MEMORY_SCOPE_AGENT);
        if (lay == 1) {
          f32x4 ov = { hv[0], hv[1], hv[2], hv[3] };
          store_wt16(out + ((size_t)bg * T_STEPS + k) * M_SZ + mloc, ov);
        }
        if (k == T_STEPS - 1) {
          f32x4 hf = { hv[0], hv[1], hv[2], hv[3] };
          f32x4 cf = { c_st[0], c_st[1], c_st[2], c_st[3] };
          store_wt16(out + OUTS + (size_t)lay * BM + (size_t)bg * M_SZ + mloc, hf);
          store_wt16(out + OUTS + 2 * (size_t)BM + (size_t)lay * BM +
                     (size_t)bg * M_SZ + mloc, cf);
        }
        asm volatile("s_waitcnt vmcnt(0)" ::: "memory");
      }
      __builtin_amdgcn_s_barrier();
      if (tid == 0) {
        const int target = k + 1;
        int prev = __hip_atomic_fetch_add(myleaf, 1, __ATOMIC_RELAXED, __HIP_MEMORY_SCOPE_AGENT);
        if ((prev & 7) == 7) {
          int pr2 = __hip_atomic_fetch_add(myroot, 1, __ATOMIC_RELAXED, __HIP_MEMORY_SCOPE_AGENT);
          if ((pr2 & 7) == 7) {
            __hip_atomic_store(myprog, target, __ATOMIC_RELAXED, __HIP_MEMORY_SCOPE_AGENT);
#pragma unroll
            for (int xx = 0; xx < 8; ++xx)
              __hip_atomic_store(bar + 16 * (36 + dom * 8 + xx), target,
                                 __ATOMIC_RELAXED, __HIP_MEMORY_SCOPE_AGENT);
          }
        }
        int guard = 0;
        while (__hip_atomic_load(rel, __ATOMIC_RELAXED, __HIP_MEMORY_SCOPE_AGENT) < target) {
          __builtin_amdgcn_s_sleep(1);
          if (++guard > (1 << 22)) break;
        }
        // cross-domain gates for step k+1
        if (k + 1 < T_STEPS) {
          int* need_p = (dom == 0) ? progB0 : progB1;
          guard = 0;
          while (__hip_atomic_load(need_p, __ATOMIC_RELAXED, __HIP_MEMORY_SCOPE_AGENT) < k + 2) {
            __builtin_amdgcn_s_sleep(1);
            if (++guard > (1 << 22)) break;
          }
          if (dom == 0 && k + 1 >= RING) {       // h0 ring reuse: B1 consumed
            guard = 0;
            while (__hip_atomic_load(progB1, __ATOMIC_RELAXED, __HIP_MEMORY_SCOPE_AGENT) < k - 30) {
              __builtin_amdgcn_s_sleep(1);
              if (++guard > (1 << 22)) break;
            }
          }
        }
        if ((k & (RING - 1)) == (RING - 1)) {
          if (leader) {
            asm volatile("buffer_inv sc0 sc1\n\ts_waitcnt vmcnt(0)" ::: "memory");
            __hip_atomic_store(relB, target, __ATOMIC_RELAXED, __HIP_MEMORY_SCOPE_AGENT);
          } else {
            guard = 0;
            while (__hip_atomic_load(relB, __ATOMIC_RELAXED, __HIP_MEMORY_SCOPE_AGENT) < target) {
              __builtin_amdgcn_s_sleep(1);
              if (++guard > (1 << 22)) break;
            }
            asm volatile("buffer_inv sc0\n\ts_waitcnt vmcnt(0)" ::: "memory");
          }
        }
      }
      __builtin_amdgcn_s_barrier();
      __builtin_amdgcn_sched_barrier(0);
    }
  } else {
    // ================= BRIDGE DOMAIN (Wx only) =================
    unsigned short* gr = lay ? g1x : g0x;
    const int rt = w >> 2, bt = w & 3;
    const int bg = bt * 16 + bl;
    const int rowb = cuD * 64 + rt * 16 + q * 4;   // lane's first gate row
    float bsv[4];
#pragma unroll
    for (int e = 0; e < 4; ++e) bsv[e] = bias[lay * G4M + rowb + e];

    for (int k = 0; k < T_STEPS; ++k) {
      const int wsl = k & (RING - 1);
      const unsigned short* ip =
          lay ? (h0r + (size_t)wsl * BM + (size_t)bg * M_SZ)     // h0[t=k]
              : (xb + ((size_t)bg * T_STEPS + k) * N_SZ);        // x[t=k]
      short8 f[32];
#pragma unroll
      for (int j = 0; j < 32; ++j) f[j] = ld16(ip + j * 32 + ko);
      asm volatile("" ::
        "v"(f[0]), "v"(f[1]), "v"(f[2]), "v"(f[3]), "v"(f[4]), "v"(f[5]),
        "v"(f[6]), "v"(f[7]), "v"(f[8]), "v"(f[9]), "v"(f[10]), "v"(f[11]),
        "v"(f[12]), "v"(f[13]), "v"(f[14]), "v"(f[15]));
      asm volatile("" ::
        "v"(f[16]), "v"(f[17]), "v"(f[18]), "v"(f[19]), "v"(f[20]), "v"(f[21]),
        "v"(f[22]), "v"(f[23]), "v"(f[24]), "v"(f[25]), "v"(f[26]), "v"(f[27]),
        "v"(f[28]), "v"(f[29]), "v"(f[30]), "v"(f[31]));
      __builtin_amdgcn_sched_barrier(0);
      f32x4 acc = { bsv[0], bsv[1], bsv[2], bsv[3] };
#pragma unroll
      for (int j = 0; j < 32; ++j)
        acc = __builtin_amdgcn_mfma_f32_16x16x32_bf16(sW[rt][j][lane], f[j], acc, 0, 0, 0);
      unsigned long long gb =
          (unsigned long long)f2bf(acc[0]) |
          ((unsigned long long)f2bf(acc[1]) << 16) |
          ((unsigned long long)f2bf(acc[2]) << 32) |
          ((unsigned long long)f2bf(acc[3]) << 48);
      __hip_atomic_store(
          (unsigned long long*)(gr + (size_t)wsl * GSTRIDE + (size_t)bg * G4M + rowb),
          gb, __ATOMIC_RELAXED, __HIP_MEMORY_SCOPE_AGENT);
      asm volatile("s_waitcnt vmcnt(0)" ::: "memory");
      __builtin_amdgcn_s_barrier();
      if (tid == 0) {
        const int target = k + 1;
        int prev = __hip_atomic_fetch_add(myleaf, 1, __ATOMIC_RELAXED, __HIP_MEMORY_SCOPE_AGENT);
        if ((prev & 7) == 7) {
          int pr2 = __hip_atomic_fetch_add(myroot, 1, __ATOMIC_RELAXED, __HIP_MEMORY_SCOPE_AGENT);
          if ((pr2 & 7) == 7) {
            __hip_atomic_store(myprog, target, __ATOMIC_RELAXED, __HIP_MEMORY_SCOPE_AGENT);
#pragma unroll
            for (int xx = 0; xx < 8; ++xx)
              __hip_atomic_store(bar + 16 * (36 + dom * 8 + xx), target,
                                 __ATOMIC_RELAXED, __HIP_MEMORY_SCOPE_AGENT);
          }
        }
        int guard = 0;
        while (__hip_atomic_load(rel, __ATOMIC_RELAXED, __HIP_MEMORY_SCOPE_AGENT) < target) {
          __builtin_amdgcn_s_sleep(1);
          if (++guard > (1 << 22)) break;
        }
        // gates for step k+1
        if (dom == 3 && k + 1 < T_STEPS) {      // need h0[k+1]
          guard = 0;
          while (__hip_atomic_load(prog0, __ATOMIC_RELAXED, __HIP_MEMORY_SCOPE_AGENT) < k + 2) {
            __builtin_amdgcn_s_sleep(1);
            if (++guard > (1 << 22)) break;
          }
        }
        if (k + 1 >= RING && k + 1 < T_STEPS) { // own gates-ring reuse
          int* cons = (dom == 2) ? prog0 : prog1;
          guard = 0;
          while (__hip_atomic_load(cons, __ATOMIC_RELAXED, __HIP_MEMORY_SCOPE_AGENT) < k - 30) {
            __builtin_amdgcn_s_sleep(1);
            if (++guard > (1 << 22)) break;
          }
        }
        if ((k & (RING - 1)) == (RING - 1)) {
          if (leader) {
            asm volatile("buffer_inv sc0 sc1\n\ts_waitcnt vmcnt(0)" ::: "memory");
            __hip_atomic_store(relB, target, __ATOMIC_RELAXED, __HIP_MEMORY_SCOPE_AGENT);
          } else {
            guard = 0;
            while (__hip_atomic_load(relB, __ATOMIC_RELAXED, __HIP_MEMORY_SCOPE_AGENT) < target) {
              __builtin_amdgcn_s_sleep(1);
              if (++guard > (1 << 22)) break;
            }
            asm volatile("buffer_inv sc0\n\ts_waitcnt vmcnt(0)" ::: "memory");
          }
        }
      }
      __builtin_amdgcn_s_barrier();
      __builtin_amdgcn_sched_barrier(0);
    }
  }
}

extern "C" void kernel_launch(void* const* d_in, const int* in_sizes, int n_in,
                              void* d_out, int out_size, void* d_ws, size_t ws_size,
                              hipStream_t stream) {
  (void)in_sizes; (void)n_in; (void)out_size; (void)ws_size;
  const float* x  = (const float*)d_in[0];
  const float* h  = (const float*)d_in[1];
  const float* c  = (const float*)d_in[2];
  const float* Wx = (const float*)d_in[3];
  const float* Wh = (const float*)d_in[4];
  const float* b  = (const float*)d_in[5];
  float* out = (float*)d_out;

  char* ws = (char*)d_ws;
  int* bar = (int*)ws;                                       // 16 KB counters
  unsigned short* h0r = (unsigned short*)(ws + 16384);                    // 4 MB
  unsigned short* h1r = (unsigned short*)(ws + 16384 + (size_t)RING * BM * 2);  // 4 MB
  unsigned short* g0x = (unsigned short*)(ws + 16384 + (size_t)RING * BM * 4);  // 16 MB
  unsigned short* g1x = (unsigned short*)(ws + 16384 + (size_t)RING * BM * 4 +
                                          (size_t)RING * GSTRIDE * 2);
  unsigned short* xb  = (unsigned short*)(ws + 16384 + (size_t)RING * BM * 4 +
                                          (size_t)RING * GSTRIDE * 4);    // 32 MB
  // ws use: 16 KB + 8 MB (h rings) + 32 MB (gates rings) + 32 MB (x) ~= 72 MB

  (void)hipMemsetAsync(ws, 0, 16384, stream);
  convert_x_kernel<<<2048, 256, 0, stream>>>(x, xb, (B_SZ * T_STEPS * N_SZ) / 4);
  init_h_kernel<<<256, 256, 0, stream>>>(h, h0r, h1r);
  lstm_pipeline<<<256, 1024, 0, stream>>>(xb, c, Wx, Wh, b, out,
                                          h0r, h1r, g0x, g1x, bar);
}

// Round 18
// 4279.234 us; speedup vs baseline: 2.7183x; 2.7183x over previous
//
#include <hip/hip_runtime.h>

// LSTM stack: B=64, T=256, N=M=1024, L=2 — 4-DOMAIN PIPELINE (r17 fixed:
// spill-free register tiling).
// 256 WGs (1/CU), 1024 threads. dom = cu&3, cuD = cu>>2 (0..63):
//   dom0: L0-serial (Wh0; 16 m-units/CU). Chain: h0[t-1] -> h0[t].
//   dom1: L1-serial (Wh1). Chain: h1[t-1] -> h1[t]; writes out.
//   dom2: Bridge0 (Wx0): g0x[t] = Wx0*x[t] + b0 (ring-throttled).
//   dom3: Bridge1 (Wx1): g1x[t] = Wx1*h0[t] + b1 (gated on L0).
// Serial CU: 8 working waves, khalf=(w>>2)&1 splits K (16 frags/wave = 64
// VGPR, no spill); each wave computes 4 gate-accs; high waves dump to LDS,
// owners (w<4) add + per-lane pointwise (no shuffles on the chain).
// Bridge CU: 16 waves, one 16x16 tile, K in two 16-frag batches (reg reuse).
// Rings (32 slots): h0,h1 bf16; g0x,g1x bf16 pre-activation gates.
// Per-domain 8x8 leaf-tree barrier + per-XCD release + prog counters; WT
// agent-atomic stores drained before arrival. Leader L2-inv at ring wrap.
// Gates: L0 waits progB0>=k+2 (+progB1 ring guard); L1 waits progB1>=k+2;
// B1 waits prog0>=k+2 (+prog1 ring guard); B0 ring-guarded on prog0.

#define T_STEPS 256
#define B_SZ 64
#define M_SZ 1024
#define N_SZ 1024
#define G4M 4096
#define BM 65536                        // B*M
#define RING 32
#define GSTRIDE ((size_t)262144)        // 64*4096 elems per gates-ring slot
#define OUTS ((size_t)16777216)         // B*T*M

typedef short short8 __attribute__((ext_vector_type(8)));
typedef float f32x4 __attribute__((ext_vector_type(4)));

static __device__ __forceinline__ unsigned short f2bf(float f) {
  union { float f; unsigned int u; } v; v.f = f;
  unsigned int u = v.u;
  unsigned int r = (u + 0x7FFFu + ((u >> 16) & 1u)) >> 16;
  return (unsigned short)r;
}
static __device__ __forceinline__ float bf2f(unsigned int us) {
  union { unsigned int u; float f; } v; v.u = (us & 0xFFFFu) << 16;
  return v.f;
}
static __device__ __forceinline__ float sigf(float x) {
  return 1.f / (1.f + __expf(-x));
}
static __device__ __forceinline__ float tanhfast(float x) {
  return 2.f / (1.f + __expf(-2.f * x)) - 1.f;
}
static __device__ __forceinline__ short8 ld16(const unsigned short* p) {
  return *reinterpret_cast<const short8*>(p);
}
static __device__ __forceinline__ void store_wt16(void* p, f32x4 v) {
  asm volatile("global_store_dwordx4 %0, %1, off sc0 sc1" :: "v"(p), "v"(v) : "memory");
}
static __device__ __forceinline__ int xcc_id() {
  int v;
  asm volatile("s_getreg_b32 %0, hwreg(HW_REG_XCC_ID)" : "=s"(v));
  return v & 7;
}

__global__ void convert_x_kernel(const float* __restrict__ x,
                                 unsigned short* __restrict__ xb, int n4) {
  int i = blockIdx.x * blockDim.x + threadIdx.x;
  int stride = gridDim.x * blockDim.x;
  for (; i < n4; i += stride) {
    float4 v = reinterpret_cast<const float4*>(x)[i];
    ushort4 o;
    o.x = f2bf(v.x); o.y = f2bf(v.y); o.z = f2bf(v.z); o.w = f2bf(v.w);
    reinterpret_cast<ushort4*>(xb)[i] = o;
  }
}

__global__ void init_h_kernel(const float* __restrict__ h,
                              unsigned short* __restrict__ h0r,
                              unsigned short* __restrict__ h1r) {
  int i = blockIdx.x * blockDim.x + threadIdx.x;  // 0..65535
  h0r[(size_t)(RING - 1) * BM + i] = f2bf(h[i]);
  h1r[(size_t)(RING - 1) * BM + i] = f2bf(h[BM + i]);
}

// bar 64B slots: leaf[dom*8+l] 0-31; root 32+dom; rel 36+dom*8+xcd;
// relB 68+dom*8+xcd; claim 100+dom*8+xcd; prog 132+dom.
__global__ __launch_bounds__(1024, 4) void lstm_pipeline(
    const unsigned short* __restrict__ xb,
    const float* __restrict__ c_in,
    const float* __restrict__ Wx,
    const float* __restrict__ Wh,
    const float* __restrict__ bias,
    float* __restrict__ out,
    unsigned short* __restrict__ h0r,
    unsigned short* __restrict__ h1r,
    unsigned short* __restrict__ g0x,
    unsigned short* __restrict__ g1x,
    int* bar) {
  __shared__ short8 sW[4][32][64];   // 128 KiB weights
  __shared__ f32x4 redS[4][4][64];   // 16 KiB serial partials [gate][bt][lane]

  const int cu = blockIdx.x;
  const int tid = threadIdx.x;
  const int lane = tid & 63;
  const int w = tid >> 6;
  const int dom = cu & 3;
  const int cuD = cu >> 2;            // 0..63
  const int lay = dom & 1;
  const bool serial = (dom < 2);
  const int q = lane >> 4;            // 0..3
  const int bl = lane & 15;
  const int ko = q * 8;
  const int xcd = xcc_id();

  // ---- stage weights ----
  {
    const float* base = serial ? (Wh + (size_t)lay * G4M * M_SZ)
                               : (Wx + (size_t)lay * G4M * N_SZ);
#pragma unroll
    for (int idx4 = 0; idx4 < 4; ++idx4) {
      for (int s = tid; s < 32 * 64; s += 1024) {
        int kt = s >> 6, ls = s & 63, r = ls & 15;
        int k0 = kt * 32 + (ls >> 4) * 8;
        int j = serial ? (idx4 * 1024 + cuD * 16 + r)
                       : (cuD * 64 + idx4 * 16 + r);
        const float* sp = base + (size_t)j * 1024 + k0;
        float4 a = reinterpret_cast<const float4*>(sp)[0];
        float4 b2 = reinterpret_cast<const float4*>(sp)[1];
        short8 wv;
        wv[0] = (short)f2bf(a.x); wv[1] = (short)f2bf(a.y);
        wv[2] = (short)f2bf(a.z); wv[3] = (short)f2bf(a.w);
        wv[4] = (short)f2bf(b2.x); wv[5] = (short)f2bf(b2.y);
        wv[6] = (short)f2bf(b2.z); wv[7] = (short)f2bf(b2.w);
        sW[idx4][kt][ls] = wv;
      }
    }
  }

  // ---- per-(dom,XCD) leader election ----
  bool leader = false;
  if (tid == 0) {
    int expected = 0;
    leader = __hip_atomic_compare_exchange_strong(
        bar + 16 * (100 + dom * 8 + xcd), &expected, cu + 1, __ATOMIC_RELAXED,
        __ATOMIC_RELAXED, __HIP_MEMORY_SCOPE_AGENT);
  }
  __syncthreads();

  int* prog0  = bar + 16 * 132;
  int* prog1  = bar + 16 * 133;
  int* progB0 = bar + 16 * 134;
  int* progB1 = bar + 16 * 135;

  // ---- startup gates ----
  if (tid == 0) {
    int guard = 0;
    if (dom == 0) {
      while (__hip_atomic_load(progB0, __ATOMIC_RELAXED, __HIP_MEMORY_SCOPE_AGENT) < 1) {
        __builtin_amdgcn_s_sleep(1); if (++guard > (1 << 22)) break;
      }
    } else if (dom == 1) {
      while (__hip_atomic_load(progB1, __ATOMIC_RELAXED, __HIP_MEMORY_SCOPE_AGENT) < 1) {
        __builtin_amdgcn_s_sleep(1); if (++guard > (1 << 22)) break;
      }
    } else if (dom == 3) {
      while (__hip_atomic_load(prog0, __ATOMIC_RELAXED, __HIP_MEMORY_SCOPE_AGENT) < 1) {
        __builtin_amdgcn_s_sleep(1); if (++guard > (1 << 22)) break;
      }
    }
  }
  __syncthreads();

  int* myleaf = bar + 16 * (dom * 8 + (cuD & 7));
  int* myroot = bar + 16 * (32 + dom);
  int* myprog = bar + 16 * (132 + dom);
  int* rel  = bar + 16 * (36 + dom * 8 + xcd);
  int* relB = bar + 16 * (68 + dom * 8 + xcd);

  if (serial) {
    // ================= SERIAL DOMAIN (Wh only) =================
    unsigned short* hr = lay ? h1r : h0r;
    unsigned short* gr = lay ? g1x : g0x;
    const int khalf = (w >> 2) & 1;       // K-half for working waves (w<8)
    const int ktb = khalf * 16;
    const int bt = w & 3;
    const int bg = bt * 16 + bl;
    const int mloc = cuD * 16 + q * 4;    // lane's first m
    const bool work = (w < 8);
    const bool ownerS = (w < 4);
    float c_st[4] = {0.f, 0.f, 0.f, 0.f};
    if (ownerS) {
#pragma unroll
      for (int e = 0; e < 4; ++e)
        c_st[e] = c_in[lay * BM + bg * M_SZ + mloc + e];
    }

    for (int k = 0; k < T_STEPS; ++k) {
      const int rs = (k + RING - 1) & (RING - 1);
      const int wsl = k & (RING - 1);
      f32x4 a0 = {0.f,0.f,0.f,0.f}, a1 = {0.f,0.f,0.f,0.f};
      f32x4 a2 = {0.f,0.f,0.f,0.f}, a3 = {0.f,0.f,0.f,0.f};
      unsigned long long gv0 = 0, gv1 = 0, gv2 = 0, gv3 = 0;
      if (work) {
        const unsigned short* hp = hr + (size_t)rs * BM + (size_t)bg * M_SZ;
        short8 f[16];
#pragma unroll
        for (int j = 0; j < 16; ++j) f[j] = ld16(hp + (ktb + j) * 32 + ko);
        if (ownerS) {   // gates loads fly alongside the h loads
          const unsigned short* gp = gr + (size_t)wsl * GSTRIDE +
                                     (size_t)bg * G4M + mloc;
          gv0 = *(const unsigned long long*)(gp);
          gv1 = *(const unsigned long long*)(gp + 1024);
          gv2 = *(const unsigned long long*)(gp + 2048);
          gv3 = *(const unsigned long long*)(gp + 3072);
        }
        asm volatile("" ::
          "v"(f[0]), "v"(f[1]), "v"(f[2]), "v"(f[3]), "v"(f[4]), "v"(f[5]),
          "v"(f[6]), "v"(f[7]), "v"(f[8]), "v"(f[9]), "v"(f[10]), "v"(f[11]),
          "v"(f[12]), "v"(f[13]), "v"(f[14]), "v"(f[15]));
        __builtin_amdgcn_sched_barrier(0);
#pragma unroll
        for (int j = 0; j < 16; ++j) {
          int kt = ktb + j;
          a0 = __builtin_amdgcn_mfma_f32_16x16x32_bf16(sW[0][kt][lane], f[j], a0, 0, 0, 0);
          a1 = __builtin_amdgcn_mfma_f32_16x16x32_bf16(sW[1][kt][lane], f[j], a1, 0, 0, 0);
          a2 = __builtin_amdgcn_mfma_f32_16x16x32_bf16(sW[2][kt][lane], f[j], a2, 0, 0, 0);
          a3 = __builtin_amdgcn_mfma_f32_16x16x32_bf16(sW[3][kt][lane], f[j], a3, 0, 0, 0);
        }
      }
      if (work && !ownerS) {
        redS[0][bt][lane] = a0; redS[1][bt][lane] = a1;
        redS[2][bt][lane] = a2; redS[3][bt][lane] = a3;
      }
      asm volatile("s_waitcnt lgkmcnt(0)" ::: "memory");
      __builtin_amdgcn_s_barrier();
      __builtin_amdgcn_sched_barrier(0);
      if (ownerS) {
        f32x4 t0 = a0 + redS[0][bt][lane];
        f32x4 t1 = a1 + redS[1][bt][lane];
        f32x4 t2 = a2 + redS[2][bt][lane];
        f32x4 t3 = a3 + redS[3][bt][lane];
        float hv[4];
#pragma unroll
        for (int e = 0; e < 4; ++e) {
          float ig = t0[e] + bf2f((unsigned int)(gv0 >> (16 * e)));
          float fg = t1[e] + bf2f((unsigned int)(gv1 >> (16 * e)));
          float gg = t2[e] + bf2f((unsigned int)(gv2 >> (16 * e)));
          float og = t3[e] + bf2f((unsigned int)(gv3 >> (16 * e)));
          float c = sigf(fg) * c_st[e] + sigf(ig) * tanhfast(gg);
          c_st[e] = c;
          hv[e] = sigf(og) * tanhfast(c);
        }
        unsigned long long hb =
            (unsigned long long)f2bf(hv[0]) |
            ((unsigned long long)f2bf(hv[1]) << 16) |
            ((unsigned long long)f2bf(hv[2]) << 32) |
            ((unsigned long long)f2bf(hv[3]) << 48);
        __hip_atomic_store(
            (unsigned long long*)(hr + (size_t)wsl * BM + (size_t)bg * M_SZ + mloc),
            hb, __ATOMIC_RELAXED, __HIP_MEMORY_SCOPE_AGENT);
        if (lay == 1) {
          f32x4 ov = { hv[0], hv[1], hv[2], hv[3] };
          store_wt16(out + ((size_t)bg * T_STEPS + k) * M_SZ + mloc, ov);
        }
        if (k == T_STEPS - 1) {
          f32x4 hf = { hv[0], hv[1], hv[2], hv[3] };
          f32x4 cf = { c_st[0], c_st[1], c_st[2], c_st[3] };
          store_wt16(out + OUTS + (size_t)lay * BM + (size_t)bg * M_SZ + mloc, hf);
          store_wt16(out + OUTS + 2 * (size_t)BM + (size_t)lay * BM +
                     (size_t)bg * M_SZ + mloc, cf);
        }
        asm volatile("s_waitcnt vmcnt(0)" ::: "memory");
      }
      __builtin_amdgcn_s_barrier();
      if (tid == 0) {
        const int target = k + 1;
        int prev = __hip_atomic_fetch_add(myleaf, 1, __ATOMIC_RELAXED, __HIP_MEMORY_SCOPE_AGENT);
        if ((prev & 7) == 7) {
          int pr2 = __hip_atomic_fetch_add(myroot, 1, __ATOMIC_RELAXED, __HIP_MEMORY_SCOPE_AGENT);
          if ((pr2 & 7) == 7) {
            __hip_atomic_store(myprog, target, __ATOMIC_RELAXED, __HIP_MEMORY_SCOPE_AGENT);
#pragma unroll
            for (int xx = 0; xx < 8; ++xx)
              __hip_atomic_store(bar + 16 * (36 + dom * 8 + xx), target,
                                 __ATOMIC_RELAXED, __HIP_MEMORY_SCOPE_AGENT);
          }
        }
        int guard = 0;
        while (__hip_atomic_load(rel, __ATOMIC_RELAXED, __HIP_MEMORY_SCOPE_AGENT) < target) {
          __builtin_amdgcn_s_sleep(1);
          if (++guard > (1 << 22)) break;
        }
        if (k + 1 < T_STEPS) {
          int* need_p = (dom == 0) ? progB0 : progB1;
          guard = 0;
          while (__hip_atomic_load(need_p, __ATOMIC_RELAXED, __HIP_MEMORY_SCOPE_AGENT) < k + 2) {
            __builtin_amdgcn_s_sleep(1);
            if (++guard > (1 << 22)) break;
          }
          if (dom == 0 && k + 1 >= RING) {
            guard = 0;
            while (__hip_atomic_load(progB1, __ATOMIC_RELAXED, __HIP_MEMORY_SCOPE_AGENT) < k - 30) {
              __builtin_amdgcn_s_sleep(1);
              if (++guard > (1 << 22)) break;
            }
          }
        }
        if ((k & (RING - 1)) == (RING - 1)) {
          if (leader) {
            asm volatile("buffer_inv sc0 sc1\n\ts_waitcnt vmcnt(0)" ::: "memory");
            __hip_atomic_store(relB, target, __ATOMIC_RELAXED, __HIP_MEMORY_SCOPE_AGENT);
          } else {
            guard = 0;
            while (__hip_atomic_load(relB, __ATOMIC_RELAXED, __HIP_MEMORY_SCOPE_AGENT) < target) {
              __builtin_amdgcn_s_sleep(1);
              if (++guard > (1 << 22)) break;
            }
            asm volatile("buffer_inv sc0\n\ts_waitcnt vmcnt(0)" ::: "memory");
          }
        }
      }
      __builtin_amdgcn_s_barrier();
      __builtin_amdgcn_sched_barrier(0);
    }
  } else {
    // ================= BRIDGE DOMAIN (Wx only) =================
    unsigned short* gr = lay ? g1x : g0x;
    const int rt = w >> 2, bt = w & 3;
    const int bg = bt * 16 + bl;
    const int rowb = cuD * 64 + rt * 16 + q * 4;   // lane's first gate row
    float bsv[4];
#pragma unroll
    for (int e = 0; e < 4; ++e) bsv[e] = bias[lay * G4M + rowb + e];

    for (int k = 0; k < T_STEPS; ++k) {
      const int wsl = k & (RING - 1);
      const unsigned short* ip =
          lay ? (h0r + (size_t)wsl * BM + (size_t)bg * M_SZ)     // h0[t=k]
              : (xb + ((size_t)bg * T_STEPS + k) * N_SZ);        // x[t=k]
      f32x4 acc = { bsv[0], bsv[1], bsv[2], bsv[3] };
      short8 f[16];
#pragma unroll
      for (int j = 0; j < 16; ++j) f[j] = ld16(ip + j * 32 + ko);
      asm volatile("" ::
        "v"(f[0]), "v"(f[1]), "v"(f[2]), "v"(f[3]), "v"(f[4]), "v"(f[5]),
        "v"(f[6]), "v"(f[7]), "v"(f[8]), "v"(f[9]), "v"(f[10]), "v"(f[11]),
        "v"(f[12]), "v"(f[13]), "v"(f[14]), "v"(f[15]));
      __builtin_amdgcn_sched_barrier(0);
#pragma unroll
      for (int j = 0; j < 16; ++j)
        acc = __builtin_amdgcn_mfma_f32_16x16x32_bf16(sW[rt][j][lane], f[j], acc, 0, 0, 0);
#pragma unroll
      for (int j = 0; j < 16; ++j) f[j] = ld16(ip + (16 + j) * 32 + ko);
      asm volatile("" ::
        "v"(f[0]), "v"(f[1]), "v"(f[2]), "v"(f[3]), "v"(f[4]), "v"(f[5]),
        "v"(f[6]), "v"(f[7]), "v"(f[8]), "v"(f[9]), "v"(f[10]), "v"(f[11]),
        "v"(f[12]), "v"(f[13]), "v"(f[14]), "v"(f[15]));
      __builtin_amdgcn_sched_barrier(0);
#pragma unroll
      for (int j = 0; j < 16; ++j)
        acc = __builtin_amdgcn_mfma_f32_16x16x32_bf16(sW[rt][16 + j][lane], f[j], acc, 0, 0, 0);
      unsigned long long gb =
          (unsigned long long)f2bf(acc[0]) |
          ((unsigned long long)f2bf(acc[1]) << 16) |
          ((unsigned long long)f2bf(acc[2]) << 32) |
          ((unsigned long long)f2bf(acc[3]) << 48);
      __hip_atomic_store(
          (unsigned long long*)(gr + (size_t)wsl * GSTRIDE + (size_t)bg * G4M + rowb),
          gb, __ATOMIC_RELAXED, __HIP_MEMORY_SCOPE_AGENT);
      asm volatile("s_waitcnt vmcnt(0)" ::: "memory");
      __builtin_amdgcn_s_barrier();
      if (tid == 0) {
        const int target = k + 1;
        int prev = __hip_atomic_fetch_add(myleaf, 1, __ATOMIC_RELAXED, __HIP_MEMORY_SCOPE_AGENT);
        if ((prev & 7) == 7) {
          int pr2 = __hip_atomic_fetch_add(myroot, 1, __ATOMIC_RELAXED, __HIP_MEMORY_SCOPE_AGENT);
          if ((pr2 & 7) == 7) {
            __hip_atomic_store(myprog, target, __ATOMIC_RELAXED, __HIP_MEMORY_SCOPE_AGENT);
#pragma unroll
            for (int xx = 0; xx < 8; ++xx)
              __hip_atomic_store(bar + 16 * (36 + dom * 8 + xx), target,
                                 __ATOMIC_RELAXED, __HIP_MEMORY_SCOPE_AGENT);
          }
        }
        int guard = 0;
        while (__hip_atomic_load(rel, __ATOMIC_RELAXED, __HIP_MEMORY_SCOPE_AGENT) < target) {
          __builtin_amdgcn_s_sleep(1);
          if (++guard > (1 << 22)) break;
        }
        if (dom == 3 && k + 1 < T_STEPS) {      // need h0[k+1]
          guard = 0;
          while (__hip_atomic_load(prog0, __ATOMIC_RELAXED, __HIP_MEMORY_SCOPE_AGENT) < k + 2) {
            __builtin_amdgcn_s_sleep(1);
            if (++guard > (1 << 22)) break;
          }
        }
        if (k + 1 >= RING && k + 1 < T_STEPS) { // own gates-ring reuse
          int* cons = (dom == 2) ? prog0 : prog1;
          guard = 0;
          while (__hip_atomic_load(cons, __ATOMIC_RELAXED, __HIP_MEMORY_SCOPE_AGENT) < k - 30) {
            __builtin_amdgcn_s_sleep(1);
            if (++guard > (1 << 22)) break;
          }
        }
        if ((k & (RING - 1)) == (RING - 1)) {
          if (leader) {
            asm volatile("buffer_inv sc0 sc1\n\ts_waitcnt vmcnt(0)" ::: "memory");
            __hip_atomic_store(relB, target, __ATOMIC_RELAXED, __HIP_MEMORY_SCOPE_AGENT);
          } else {
            guard = 0;
            while (__hip_atomic_load(relB, __ATOMIC_RELAXED, __HIP_MEMORY_SCOPE_AGENT) < target) {
              __builtin_amdgcn_s_sleep(1);
              if (++guard > (1 << 22)) break;
            }
            asm volatile("buffer_inv sc0\n\ts_waitcnt vmcnt(0)" ::: "memory");
          }
        }
      }
      __builtin_amdgcn_s_barrier();
      __builtin_amdgcn_sched_barrier(0);
    }
  }
}

extern "C" void kernel_launch(void* const* d_in, const int* in_sizes, int n_in,
                              void* d_out, int out_size, void* d_ws, size_t ws_size,
                              hipStream_t stream) {
  (void)in_sizes; (void)n_in; (void)out_size; (void)ws_size;
  const float* x  = (const float*)d_in[0];
  const float* h  = (const float*)d_in[1];
  const float* c  = (const float*)d_in[2];
  const float* Wx = (const float*)d_in[3];
  const float* Wh = (const float*)d_in[4];
  const float* b  = (const float*)d_in[5];
  float* out = (float*)d_out;

  char* ws = (char*)d_ws;
  int* bar = (int*)ws;                                       // 16 KB counters
  unsigned short* h0r = (unsigned short*)(ws + 16384);
  unsigned short* h1r = (unsigned short*)(ws + 16384 + (size_t)RING * BM * 2);
  unsigned short* g0x = (unsigned short*)(ws + 16384 + (size_t)RING * BM * 4);
  unsigned short* g1x = (unsigned short*)(ws + 16384 + (size_t)RING * BM * 4 +
                                          (size_t)RING * GSTRIDE * 2);
  unsigned short* xb  = (unsigned short*)(ws + 16384 + (size_t)RING * BM * 4 +
                                          (size_t)RING * GSTRIDE * 4);
  // ws use: 16 KB + 8 MB (h rings) + 32 MB (gates rings) + 32 MB (x) ~= 72 MB

  (void)hipMemsetAsync(ws, 0, 16384, stream);
  convert_x_kernel<<<2048, 256, 0, stream>>>(x, xb, (B_SZ * T_STEPS * N_SZ) / 4);
  init_h_kernel<<<256, 256, 0, stream>>>(h, h0r, h1r);
  lstm_pipeline<<<256, 1024, 0, stream>>>(xb, c, Wx, Wh, b, out,
                                          h0r, h1r, g0x, g1x, bar);
}

// Round 19
// 2737.938 us; speedup vs baseline: 4.2486x; 1.5629x over previous
//
#include <hip/hip_runtime.h>

// LSTM stack: B=64, T=256, N=M=1024, L=2 — 4-DOMAIN PIPELINE (r18 + bridge
// restructure: K-split bridge waves, 1x load batch, 2x accs, LDS reduce).
// 256 WGs (1/CU), 1024 threads. dom = cu&3, cuD = cu>>2 (0..63):
//   dom0: L0-serial (Wh0; 16 m-units/CU). Chain: h0[t-1] -> h0[t].
//   dom1: L1-serial (Wh1). Chain: h1[t-1] -> h1[t]; writes out.
//   dom2: Bridge0 (Wx0): g0x[t] = Wx0*x[t] + b0 (ring-throttled).
//   dom3: Bridge1 (Wx1): g1x[t] = Wx1*h0[t] + b1 (gated on L0).
// Serial CU: 8 working waves, khalf splits K (16 frags/wave); 4 gate-accs per
// wave; LDS reduce; owners do per-lane pointwise (no shuffles on the chain).
// Bridge CU (NEW): 16 waves = (khalf, rg, bt); each wave loads its K-half of
// 16 input rows ONCE (16 frags) and computes 2 rt-accs (rt=rg*2, rg*2+1);
// khalf=1 waves dump to LDS; khalf=0 owners add + bias + store. Input re-read
// 4x -> 2x, one load batch instead of two serialized.
// Rings (32 slots): h0,h1 bf16; g0x,g1x bf16 pre-activation gates.
// Per-domain 8x8 leaf-tree barrier + per-XCD release + prog counters; WT
// agent-atomic stores drained before arrival. Leader L2-inv at ring wrap.

#define T_STEPS 256
#define B_SZ 64
#define M_SZ 1024
#define N_SZ 1024
#define G4M 4096
#define BM 65536                        // B*M
#define RING 32
#define GSTRIDE ((size_t)262144)        // 64*4096 elems per gates-ring slot
#define OUTS ((size_t)16777216)         // B*T*M

typedef short short8 __attribute__((ext_vector_type(8)));
typedef float f32x4 __attribute__((ext_vector_type(4)));

static __device__ __forceinline__ unsigned short f2bf(float f) {
  union { float f; unsigned int u; } v; v.f = f;
  unsigned int u = v.u;
  unsigned int r = (u + 0x7FFFu + ((u >> 16) & 1u)) >> 16;
  return (unsigned short)r;
}
static __device__ __forceinline__ float bf2f(unsigned int us) {
  union { unsigned int u; float f; } v; v.u = (us & 0xFFFFu) << 16;
  return v.f;
}
static __device__ __forceinline__ float sigf(float x) {
  return 1.f / (1.f + __expf(-x));
}
static __device__ __forceinline__ float tanhfast(float x) {
  return 2.f / (1.f + __expf(-2.f * x)) - 1.f;
}
static __device__ __forceinline__ short8 ld16(const unsigned short* p) {
  return *reinterpret_cast<const short8*>(p);
}
static __device__ __forceinline__ void store_wt16(void* p, f32x4 v) {
  asm volatile("global_store_dwordx4 %0, %1, off sc0 sc1" :: "v"(p), "v"(v) : "memory");
}
static __device__ __forceinline__ int xcc_id() {
  int v;
  asm volatile("s_getreg_b32 %0, hwreg(HW_REG_XCC_ID)" : "=s"(v));
  return v & 7;
}

__global__ void convert_x_kernel(const float* __restrict__ x,
                                 unsigned short* __restrict__ xb, int n4) {
  int i = blockIdx.x * blockDim.x + threadIdx.x;
  int stride = gridDim.x * blockDim.x;
  for (; i < n4; i += stride) {
    float4 v = reinterpret_cast<const float4*>(x)[i];
    ushort4 o;
    o.x = f2bf(v.x); o.y = f2bf(v.y); o.z = f2bf(v.z); o.w = f2bf(v.w);
    reinterpret_cast<ushort4*>(xb)[i] = o;
  }
}

__global__ void init_h_kernel(const float* __restrict__ h,
                              unsigned short* __restrict__ h0r,
                              unsigned short* __restrict__ h1r) {
  int i = blockIdx.x * blockDim.x + threadIdx.x;  // 0..65535
  h0r[(size_t)(RING - 1) * BM + i] = f2bf(h[i]);
  h1r[(size_t)(RING - 1) * BM + i] = f2bf(h[BM + i]);
}

// bar 64B slots: leaf[dom*8+l] 0-31; root 32+dom; rel 36+dom*8+xcd;
// relB 68+dom*8+xcd; claim 100+dom*8+xcd; prog 132+dom.
__global__ __launch_bounds__(1024, 4) void lstm_pipeline(
    const unsigned short* __restrict__ xb,
    const float* __restrict__ c_in,
    const float* __restrict__ Wx,
    const float* __restrict__ Wh,
    const float* __restrict__ bias,
    float* __restrict__ out,
    unsigned short* __restrict__ h0r,
    unsigned short* __restrict__ h1r,
    unsigned short* __restrict__ g0x,
    unsigned short* __restrict__ g1x,
    int* bar) {
  __shared__ short8 sW[4][32][64];   // 128 KiB weights
  __shared__ f32x4 redS[4][4][64];   // 16 KiB partials [gate/rt][bt][lane]

  const int cu = blockIdx.x;
  const int tid = threadIdx.x;
  const int lane = tid & 63;
  const int w = tid >> 6;
  const int dom = cu & 3;
  const int cuD = cu >> 2;            // 0..63
  const int lay = dom & 1;
  const bool serial = (dom < 2);
  const int q = lane >> 4;            // 0..3
  const int bl = lane & 15;
  const int ko = q * 8;
  const int xcd = xcc_id();

  // ---- stage weights ----
  {
    const float* base = serial ? (Wh + (size_t)lay * G4M * M_SZ)
                               : (Wx + (size_t)lay * G4M * N_SZ);
#pragma unroll
    for (int idx4 = 0; idx4 < 4; ++idx4) {
      for (int s = tid; s < 32 * 64; s += 1024) {
        int kt = s >> 6, ls = s & 63, r = ls & 15;
        int k0 = kt * 32 + (ls >> 4) * 8;
        int j = serial ? (idx4 * 1024 + cuD * 16 + r)
                       : (cuD * 64 + idx4 * 16 + r);
        const float* sp = base + (size_t)j * 1024 + k0;
        float4 a = reinterpret_cast<const float4*>(sp)[0];
        float4 b2 = reinterpret_cast<const float4*>(sp)[1];
        short8 wv;
        wv[0] = (short)f2bf(a.x); wv[1] = (short)f2bf(a.y);
        wv[2] = (short)f2bf(a.z); wv[3] = (short)f2bf(a.w);
        wv[4] = (short)f2bf(b2.x); wv[5] = (short)f2bf(b2.y);
        wv[6] = (short)f2bf(b2.z); wv[7] = (short)f2bf(b2.w);
        sW[idx4][kt][ls] = wv;
      }
    }
  }

  // ---- per-(dom,XCD) leader election ----
  bool leader = false;
  if (tid == 0) {
    int expected = 0;
    leader = __hip_atomic_compare_exchange_strong(
        bar + 16 * (100 + dom * 8 + xcd), &expected, cu + 1, __ATOMIC_RELAXED,
        __ATOMIC_RELAXED, __HIP_MEMORY_SCOPE_AGENT);
  }
  __syncthreads();

  int* prog0  = bar + 16 * 132;
  int* prog1  = bar + 16 * 133;
  int* progB0 = bar + 16 * 134;
  int* progB1 = bar + 16 * 135;

  // ---- startup gates ----
  if (tid == 0) {
    int guard = 0;
    if (dom == 0) {
      while (__hip_atomic_load(progB0, __ATOMIC_RELAXED, __HIP_MEMORY_SCOPE_AGENT) < 1) {
        __builtin_amdgcn_s_sleep(1); if (++guard > (1 << 22)) break;
      }
    } else if (dom == 1) {
      while (__hip_atomic_load(progB1, __ATOMIC_RELAXED, __HIP_MEMORY_SCOPE_AGENT) < 1) {
        __builtin_amdgcn_s_sleep(1); if (++guard > (1 << 22)) break;
      }
    } else if (dom == 3) {
      while (__hip_atomic_load(prog0, __ATOMIC_RELAXED, __HIP_MEMORY_SCOPE_AGENT) < 1) {
        __builtin_amdgcn_s_sleep(1); if (++guard > (1 << 22)) break;
      }
    }
  }
  __syncthreads();

  int* myleaf = bar + 16 * (dom * 8 + (cuD & 7));
  int* myroot = bar + 16 * (32 + dom);
  int* myprog = bar + 16 * (132 + dom);
  int* rel  = bar + 16 * (36 + dom * 8 + xcd);
  int* relB = bar + 16 * (68 + dom * 8 + xcd);

  if (serial) {
    // ================= SERIAL DOMAIN (Wh only) =================
    unsigned short* hr = lay ? h1r : h0r;
    unsigned short* gr = lay ? g1x : g0x;
    const int khalf = (w >> 2) & 1;       // K-half for working waves (w<8)
    const int ktb = khalf * 16;
    const int bt = w & 3;
    const int bg = bt * 16 + bl;
    const int mloc = cuD * 16 + q * 4;    // lane's first m
    const bool work = (w < 8);
    const bool ownerS = (w < 4);
    float c_st[4] = {0.f, 0.f, 0.f, 0.f};
    if (ownerS) {
#pragma unroll
      for (int e = 0; e < 4; ++e)
        c_st[e] = c_in[lay * BM + bg * M_SZ + mloc + e];
    }

    for (int k = 0; k < T_STEPS; ++k) {
      const int rs = (k + RING - 1) & (RING - 1);
      const int wsl = k & (RING - 1);
      f32x4 a0 = {0.f,0.f,0.f,0.f}, a1 = {0.f,0.f,0.f,0.f};
      f32x4 a2 = {0.f,0.f,0.f,0.f}, a3 = {0.f,0.f,0.f,0.f};
      unsigned long long gv0 = 0, gv1 = 0, gv2 = 0, gv3 = 0;
      if (work) {
        const unsigned short* hp = hr + (size_t)rs * BM + (size_t)bg * M_SZ;
        short8 f[16];
#pragma unroll
        for (int j = 0; j < 16; ++j) f[j] = ld16(hp + (ktb + j) * 32 + ko);
        if (ownerS) {   // gates loads fly alongside the h loads
          const unsigned short* gp = gr + (size_t)wsl * GSTRIDE +
                                     (size_t)bg * G4M + mloc;
          gv0 = *(const unsigned long long*)(gp);
          gv1 = *(const unsigned long long*)(gp + 1024);
          gv2 = *(const unsigned long long*)(gp + 2048);
          gv3 = *(const unsigned long long*)(gp + 3072);
        }
        asm volatile("" ::
          "v"(f[0]), "v"(f[1]), "v"(f[2]), "v"(f[3]), "v"(f[4]), "v"(f[5]),
          "v"(f[6]), "v"(f[7]), "v"(f[8]), "v"(f[9]), "v"(f[10]), "v"(f[11]),
          "v"(f[12]), "v"(f[13]), "v"(f[14]), "v"(f[15]));
        __builtin_amdgcn_sched_barrier(0);
#pragma unroll
        for (int j = 0; j < 16; ++j) {
          int kt = ktb + j;
          a0 = __builtin_amdgcn_mfma_f32_16x16x32_bf16(sW[0][kt][lane], f[j], a0, 0, 0, 0);
          a1 = __builtin_amdgcn_mfma_f32_16x16x32_bf16(sW[1][kt][lane], f[j], a1, 0, 0, 0);
          a2 = __builtin_amdgcn_mfma_f32_16x16x32_bf16(sW[2][kt][lane], f[j], a2, 0, 0, 0);
          a3 = __builtin_amdgcn_mfma_f32_16x16x32_bf16(sW[3][kt][lane], f[j], a3, 0, 0, 0);
        }
      }
      if (work && !ownerS) {
        redS[0][bt][lane] = a0; redS[1][bt][lane] = a1;
        redS[2][bt][lane] = a2; redS[3][bt][lane] = a3;
      }
      asm volatile("s_waitcnt lgkmcnt(0)" ::: "memory");
      __builtin_amdgcn_s_barrier();
      __builtin_amdgcn_sched_barrier(0);
      if (ownerS) {
        f32x4 t0 = a0 + redS[0][bt][lane];
        f32x4 t1 = a1 + redS[1][bt][lane];
        f32x4 t2 = a2 + redS[2][bt][lane];
        f32x4 t3 = a3 + redS[3][bt][lane];
        float hv[4];
#pragma unroll
        for (int e = 0; e < 4; ++e) {
          float ig = t0[e] + bf2f((unsigned int)(gv0 >> (16 * e)));
          float fg = t1[e] + bf2f((unsigned int)(gv1 >> (16 * e)));
          float gg = t2[e] + bf2f((unsigned int)(gv2 >> (16 * e)));
          float og = t3[e] + bf2f((unsigned int)(gv3 >> (16 * e)));
          float c = sigf(fg) * c_st[e] + sigf(ig) * tanhfast(gg);
          c_st[e] = c;
          hv[e] = sigf(og) * tanhfast(c);
        }
        unsigned long long hb =
            (unsigned long long)f2bf(hv[0]) |
            ((unsigned long long)f2bf(hv[1]) << 16) |
            ((unsigned long long)f2bf(hv[2]) << 32) |
            ((unsigned long long)f2bf(hv[3]) << 48);
        __hip_atomic_store(
            (unsigned long long*)(hr + (size_t)wsl * BM + (size_t)bg * M_SZ + mloc),
            hb, __ATOMIC_RELAXED, __HIP_MEMORY_SCOPE_AGENT);
        if (lay == 1) {
          f32x4 ov = { hv[0], hv[1], hv[2], hv[3] };
          store_wt16(out + ((size_t)bg * T_STEPS + k) * M_SZ + mloc, ov);
        }
        if (k == T_STEPS - 1) {
          f32x4 hf = { hv[0], hv[1], hv[2], hv[3] };
          f32x4 cf = { c_st[0], c_st[1], c_st[2], c_st[3] };
          store_wt16(out + OUTS + (size_t)lay * BM + (size_t)bg * M_SZ + mloc, hf);
          store_wt16(out + OUTS + 2 * (size_t)BM + (size_t)lay * BM +
                     (size_t)bg * M_SZ + mloc, cf);
        }
        asm volatile("s_waitcnt vmcnt(0)" ::: "memory");
      }
      __builtin_amdgcn_s_barrier();
      if (tid == 0) {
        const int target = k + 1;
        int prev = __hip_atomic_fetch_add(myleaf, 1, __ATOMIC_RELAXED, __HIP_MEMORY_SCOPE_AGENT);
        if ((prev & 7) == 7) {
          int pr2 = __hip_atomic_fetch_add(myroot, 1, __ATOMIC_RELAXED, __HIP_MEMORY_SCOPE_AGENT);
          if ((pr2 & 7) == 7) {
            __hip_atomic_store(myprog, target, __ATOMIC_RELAXED, __HIP_MEMORY_SCOPE_AGENT);
#pragma unroll
            for (int xx = 0; xx < 8; ++xx)
              __hip_atomic_store(bar + 16 * (36 + dom * 8 + xx), target,
                                 __ATOMIC_RELAXED, __HIP_MEMORY_SCOPE_AGENT);
          }
        }
        int guard = 0;
        while (__hip_atomic_load(rel, __ATOMIC_RELAXED, __HIP_MEMORY_SCOPE_AGENT) < target) {
          __builtin_amdgcn_s_sleep(1);
          if (++guard > (1 << 22)) break;
        }
        if (k + 1 < T_STEPS) {
          int* need_p = (dom == 0) ? progB0 : progB1;
          guard = 0;
          while (__hip_atomic_load(need_p, __ATOMIC_RELAXED, __HIP_MEMORY_SCOPE_AGENT) < k + 2) {
            __builtin_amdgcn_s_sleep(1);
            if (++guard > (1 << 22)) break;
          }
          if (dom == 0 && k + 1 >= RING) {
            guard = 0;
            while (__hip_atomic_load(progB1, __ATOMIC_RELAXED, __HIP_MEMORY_SCOPE_AGENT) < k - 30) {
              __builtin_amdgcn_s_sleep(1);
              if (++guard > (1 << 22)) break;
            }
          }
        }
        if ((k & (RING - 1)) == (RING - 1)) {
          if (leader) {
            asm volatile("buffer_inv sc0 sc1\n\ts_waitcnt vmcnt(0)" ::: "memory");
            __hip_atomic_store(relB, target, __ATOMIC_RELAXED, __HIP_MEMORY_SCOPE_AGENT);
          } else {
            guard = 0;
            while (__hip_atomic_load(relB, __ATOMIC_RELAXED, __HIP_MEMORY_SCOPE_AGENT) < target) {
              __builtin_amdgcn_s_sleep(1);
              if (++guard > (1 << 22)) break;
            }
            asm volatile("buffer_inv sc0\n\ts_waitcnt vmcnt(0)" ::: "memory");
          }
        }
      }
      __builtin_amdgcn_s_barrier();
      __builtin_amdgcn_sched_barrier(0);
    }
  } else {
    // ================= BRIDGE DOMAIN (Wx only; K-split waves) =================
    unsigned short* gr = lay ? g1x : g0x;
    const int khB = w >> 3;             // K-half
    const int rg = (w >> 2) & 1;        // rt pair: rt = rg*2, rg*2+1
    const int bt = w & 3;
    const int bg = bt * 16 + bl;
    const int ktbB = khB * 16;
    const int rt0 = rg * 2, rt1 = rg * 2 + 1;
    const int row0 = cuD * 64 + rt0 * 16 + q * 4;
    const int row1 = cuD * 64 + rt1 * 16 + q * 4;
    float bs0[4], bs1[4];
#pragma unroll
    for (int e = 0; e < 4; ++e) {
      bs0[e] = bias[lay * G4M + row0 + e];
      bs1[e] = bias[lay * G4M + row1 + e];
    }

    for (int k = 0; k < T_STEPS; ++k) {
      const int wsl = k & (RING - 1);
      const unsigned short* ip =
          lay ? (h0r + (size_t)wsl * BM + (size_t)bg * M_SZ)     // h0[t=k]
              : (xb + ((size_t)bg * T_STEPS + k) * N_SZ);        // x[t=k]
      f32x4 acc0 = {0.f,0.f,0.f,0.f}, acc1 = {0.f,0.f,0.f,0.f};
      if (khB == 0) {
#pragma unroll
        for (int e = 0; e < 4; ++e) { acc0[e] = bs0[e]; acc1[e] = bs1[e]; }
      }
      short8 f[16];
#pragma unroll
      for (int j = 0; j < 16; ++j) f[j] = ld16(ip + (ktbB + j) * 32 + ko);
      asm volatile("" ::
        "v"(f[0]), "v"(f[1]), "v"(f[2]), "v"(f[3]), "v"(f[4]), "v"(f[5]),
        "v"(f[6]), "v"(f[7]), "v"(f[8]), "v"(f[9]), "v"(f[10]), "v"(f[11]),
        "v"(f[12]), "v"(f[13]), "v"(f[14]), "v"(f[15]));
      __builtin_amdgcn_sched_barrier(0);
#pragma unroll
      for (int j = 0; j < 16; ++j) {
        int kt = ktbB + j;
        acc0 = __builtin_amdgcn_mfma_f32_16x16x32_bf16(sW[rt0][kt][lane], f[j], acc0, 0, 0, 0);
        acc1 = __builtin_amdgcn_mfma_f32_16x16x32_bf16(sW[rt1][kt][lane], f[j], acc1, 0, 0, 0);
      }
      if (khB == 1) {
        redS[rt0][bt][lane] = acc0;
        redS[rt1][bt][lane] = acc1;
      }
      asm volatile("s_waitcnt lgkmcnt(0)" ::: "memory");
      __builtin_amdgcn_s_barrier();
      __builtin_amdgcn_sched_barrier(0);
      if (khB == 0) {
        f32x4 t0 = acc0 + redS[rt0][bt][lane];
        f32x4 t1 = acc1 + redS[rt1][bt][lane];
        unsigned long long gb0 =
            (unsigned long long)f2bf(t0[0]) |
            ((unsigned long long)f2bf(t0[1]) << 16) |
            ((unsigned long long)f2bf(t0[2]) << 32) |
            ((unsigned long long)f2bf(t0[3]) << 48);
        unsigned long long gb1 =
            (unsigned long long)f2bf(t1[0]) |
            ((unsigned long long)f2bf(t1[1]) << 16) |
            ((unsigned long long)f2bf(t1[2]) << 32) |
            ((unsigned long long)f2bf(t1[3]) << 48);
        unsigned short* gbse = gr + (size_t)wsl * GSTRIDE + (size_t)bg * G4M;
        __hip_atomic_store((unsigned long long*)(gbse + row0), gb0,
                           __ATOMIC_RELAXED, __HIP_MEMORY_SCOPE_AGENT);
        __hip_atomic_store((unsigned long long*)(gbse + row1), gb1,
                           __ATOMIC_RELAXED, __HIP_MEMORY_SCOPE_AGENT);
        asm volatile("s_waitcnt vmcnt(0)" ::: "memory");
      }
      __builtin_amdgcn_s_barrier();
      if (tid == 0) {
        const int target = k + 1;
        int prev = __hip_atomic_fetch_add(myleaf, 1, __ATOMIC_RELAXED, __HIP_MEMORY_SCOPE_AGENT);
        if ((prev & 7) == 7) {
          int pr2 = __hip_atomic_fetch_add(myroot, 1, __ATOMIC_RELAXED, __HIP_MEMORY_SCOPE_AGENT);
          if ((pr2 & 7) == 7) {
            __hip_atomic_store(myprog, target, __ATOMIC_RELAXED, __HIP_MEMORY_SCOPE_AGENT);
#pragma unroll
            for (int xx = 0; xx < 8; ++xx)
              __hip_atomic_store(bar + 16 * (36 + dom * 8 + xx), target,
                                 __ATOMIC_RELAXED, __HIP_MEMORY_SCOPE_AGENT);
          }
        }
        int guard = 0;
        while (__hip_atomic_load(rel, __ATOMIC_RELAXED, __HIP_MEMORY_SCOPE_AGENT) < target) {
          __builtin_amdgcn_s_sleep(1);
          if (++guard > (1 << 22)) break;
        }
        if (dom == 3 && k + 1 < T_STEPS) {      // need h0[k+1]
          guard = 0;
          while (__hip_atomic_load(prog0, __ATOMIC_RELAXED, __HIP_MEMORY_SCOPE_AGENT) < k + 2) {
            __builtin_amdgcn_s_sleep(1);
            if (++guard > (1 << 22)) break;
          }
        }
        if (k + 1 >= RING && k + 1 < T_STEPS) { // own gates-ring reuse
          int* cons = (dom == 2) ? prog0 : prog1;
          guard = 0;
          while (__hip_atomic_load(cons, __ATOMIC_RELAXED, __HIP_MEMORY_SCOPE_AGENT) < k - 30) {
            __builtin_amdgcn_s_sleep(1);
            if (++guard > (1 << 22)) break;
          }
        }
        if ((k & (RING - 1)) == (RING - 1)) {
          if (leader) {
            asm volatile("buffer_inv sc0 sc1\n\ts_waitcnt vmcnt(0)" ::: "memory");
            __hip_atomic_store(relB, target, __ATOMIC_RELAXED, __HIP_MEMORY_SCOPE_AGENT);
          } else {
            guard = 0;
            while (__hip_atomic_load(relB, __ATOMIC_RELAXED, __HIP_MEMORY_SCOPE_AGENT) < target) {
              __builtin_amdgcn_s_sleep(1);
              if (++guard > (1 << 22)) break;
            }
            asm volatile("buffer_inv sc0\n\ts_waitcnt vmcnt(0)" ::: "memory");
          }
        }
      }
      __builtin_amdgcn_s_barrier();
      __builtin_amdgcn_sched_barrier(0);
    }
  }
}

extern "C" void kernel_launch(void* const* d_in, const int* in_sizes, int n_in,
                              void* d_out, int out_size, void* d_ws, size_t ws_size,
                              hipStream_t stream) {
  (void)in_sizes; (void)n_in; (void)out_size; (void)ws_size;
  const float* x  = (const float*)d_in[0];
  const float* h  = (const float*)d_in[1];
  const float* c  = (const float*)d_in[2];
  const float* Wx = (const float*)d_in[3];
  const float* Wh = (const float*)d_in[4];
  const float* b  = (const float*)d_in[5];
  float* out = (float*)d_out;

  char* ws = (char*)d_ws;
  int* bar = (int*)ws;                                       // 16 KB counters
  unsigned short* h0r = (unsigned short*)(ws + 16384);
  unsigned short* h1r = (unsigned short*)(ws + 16384 + (size_t)RING * BM * 2);
  unsigned short* g0x = (unsigned short*)(ws + 16384 + (size_t)RING * BM * 4);
  unsigned short* g1x = (unsigned short*)(ws + 16384 + (size_t)RING * BM * 4 +
                                          (size_t)RING * GSTRIDE * 2);
  unsigned short* xb  = (unsigned short*)(ws + 16384 + (size_t)RING * BM * 4 +
                                          (size_t)RING * GSTRIDE * 4);
  // ws use: 16 KB + 8 MB (h rings) + 32 MB (gates rings) + 32 MB (x) ~= 72 MB

  (void)hipMemsetAsync(ws, 0, 16384, stream);
  convert_x_kernel<<<2048, 256, 0, stream>>>(x, xb, (B_SZ * T_STEPS * N_SZ) / 4);
  init_h_kernel<<<256, 256, 0, stream>>>(h, h0r, h1r);
  lstm_pipeline<<<256, 1024, 0, stream>>>(xb, c, Wx, Wh, b, out,
                                          h0r, h1r, g0x, g1x, bar);
}

// Round 20
// 2707.072 us; speedup vs baseline: 4.2970x; 1.0114x over previous
//
#include <hip/hip_runtime.h>

// LSTM stack: B=64, T=256, N=M=1024, L=2 — 4-DOMAIN PIPELINE (r19 + L1
// out-store drain fix: vmcnt(1) so the HBM out-store flies across arrival).
// 256 WGs (1/CU), 1024 threads. dom = cu&3, cuD = cu>>2 (0..63):
//   dom0: L0-serial (Wh0; 16 m-units/CU). Chain: h0[t-1] -> h0[t].
//   dom1: L1-serial (Wh1). Chain: h1[t-1] -> h1[t]; writes out.
//   dom2: Bridge0 (Wx0): g0x[t] = Wx0*x[t] + b0 (ring-throttled).
//   dom3: Bridge1 (Wx1): g1x[t] = Wx1*h0[t] + b1 (gated on L0).
// Serial CU: 8 working waves, khalf splits K (16 frags/wave); 4 gate-accs per
// wave; LDS reduce; owners do per-lane pointwise (no shuffles on the chain).
// L1 owners issue h-store FIRST, then out store, and drain vmcnt(1): in-order
// vmcnt retirement guarantees the h-store is visible at arrival while the HBM
// out-store stays in flight (kernel-boundary fence covers it; h1[255] and the
// finals have no on-device consumers).
// Bridge CU: 16 waves = (khalf, rg, bt); each wave loads its K-half of 16
// input rows ONCE and computes 2 rt-accs; khalf=1 dumps to LDS; khalf=0
// owners add + bias + store gates (bf16).
// Rings (32 slots): h0,h1 bf16; g0x,g1x bf16 pre-activation gates.
// Per-domain 8x8 leaf-tree barrier + per-XCD release + prog counters; WT
// agent-atomic stores drained before arrival. Leader L2-inv at ring wrap.

#define T_STEPS 256
#define B_SZ 64
#define M_SZ 1024
#define N_SZ 1024
#define G4M 4096
#define BM 65536                        // B*M
#define RING 32
#define GSTRIDE ((size_t)262144)        // 64*4096 elems per gates-ring slot
#define OUTS ((size_t)16777216)         // B*T*M

typedef short short8 __attribute__((ext_vector_type(8)));
typedef float f32x4 __attribute__((ext_vector_type(4)));

static __device__ __forceinline__ unsigned short f2bf(float f) {
  union { float f; unsigned int u; } v; v.f = f;
  unsigned int u = v.u;
  unsigned int r = (u + 0x7FFFu + ((u >> 16) & 1u)) >> 16;
  return (unsigned short)r;
}
static __device__ __forceinline__ float bf2f(unsigned int us) {
  union { unsigned int u; float f; } v; v.u = (us & 0xFFFFu) << 16;
  return v.f;
}
static __device__ __forceinline__ float sigf(float x) {
  return 1.f / (1.f + __expf(-x));
}
static __device__ __forceinline__ float tanhfast(float x) {
  return 2.f / (1.f + __expf(-2.f * x)) - 1.f;
}
static __device__ __forceinline__ short8 ld16(const unsigned short* p) {
  return *reinterpret_cast<const short8*>(p);
}
static __device__ __forceinline__ void store_wt16(void* p, f32x4 v) {
  asm volatile("global_store_dwordx4 %0, %1, off sc0 sc1" :: "v"(p), "v"(v) : "memory");
}
static __device__ __forceinline__ int xcc_id() {
  int v;
  asm volatile("s_getreg_b32 %0, hwreg(HW_REG_XCC_ID)" : "=s"(v));
  return v & 7;
}

__global__ void convert_x_kernel(const float* __restrict__ x,
                                 unsigned short* __restrict__ xb, int n4) {
  int i = blockIdx.x * blockDim.x + threadIdx.x;
  int stride = gridDim.x * blockDim.x;
  for (; i < n4; i += stride) {
    float4 v = reinterpret_cast<const float4*>(x)[i];
    ushort4 o;
    o.x = f2bf(v.x); o.y = f2bf(v.y); o.z = f2bf(v.z); o.w = f2bf(v.w);
    reinterpret_cast<ushort4*>(xb)[i] = o;
  }
}

__global__ void init_h_kernel(const float* __restrict__ h,
                              unsigned short* __restrict__ h0r,
                              unsigned short* __restrict__ h1r) {
  int i = blockIdx.x * blockDim.x + threadIdx.x;  // 0..65535
  h0r[(size_t)(RING - 1) * BM + i] = f2bf(h[i]);
  h1r[(size_t)(RING - 1) * BM + i] = f2bf(h[BM + i]);
}

// bar 64B slots: leaf[dom*8+l] 0-31; root 32+dom; rel 36+dom*8+xcd;
// relB 68+dom*8+xcd; claim 100+dom*8+xcd; prog 132+dom.
__global__ __launch_bounds__(1024, 4) void lstm_pipeline(
    const unsigned short* __restrict__ xb,
    const float* __restrict__ c_in,
    const float* __restrict__ Wx,
    const float* __restrict__ Wh,
    const float* __restrict__ bias,
    float* __restrict__ out,
    unsigned short* __restrict__ h0r,
    unsigned short* __restrict__ h1r,
    unsigned short* __restrict__ g0x,
    unsigned short* __restrict__ g1x,
    int* bar) {
  __shared__ short8 sW[4][32][64];   // 128 KiB weights
  __shared__ f32x4 redS[4][4][64];   // 16 KiB partials [gate/rt][bt][lane]

  const int cu = blockIdx.x;
  const int tid = threadIdx.x;
  const int lane = tid & 63;
  const int w = tid >> 6;
  const int dom = cu & 3;
  const int cuD = cu >> 2;            // 0..63
  const int lay = dom & 1;
  const bool serial = (dom < 2);
  const int q = lane >> 4;            // 0..3
  const int bl = lane & 15;
  const int ko = q * 8;
  const int xcd = xcc_id();

  // ---- stage weights ----
  {
    const float* base = serial ? (Wh + (size_t)lay * G4M * M_SZ)
                               : (Wx + (size_t)lay * G4M * N_SZ);
#pragma unroll
    for (int idx4 = 0; idx4 < 4; ++idx4) {
      for (int s = tid; s < 32 * 64; s += 1024) {
        int kt = s >> 6, ls = s & 63, r = ls & 15;
        int k0 = kt * 32 + (ls >> 4) * 8;
        int j = serial ? (idx4 * 1024 + cuD * 16 + r)
                       : (cuD * 64 + idx4 * 16 + r);
        const float* sp = base + (size_t)j * 1024 + k0;
        float4 a = reinterpret_cast<const float4*>(sp)[0];
        float4 b2 = reinterpret_cast<const float4*>(sp)[1];
        short8 wv;
        wv[0] = (short)f2bf(a.x); wv[1] = (short)f2bf(a.y);
        wv[2] = (short)f2bf(a.z); wv[3] = (short)f2bf(a.w);
        wv[4] = (short)f2bf(b2.x); wv[5] = (short)f2bf(b2.y);
        wv[6] = (short)f2bf(b2.z); wv[7] = (short)f2bf(b2.w);
        sW[idx4][kt][ls] = wv;
      }
    }
  }

  // ---- per-(dom,XCD) leader election ----
  bool leader = false;
  if (tid == 0) {
    int expected = 0;
    leader = __hip_atomic_compare_exchange_strong(
        bar + 16 * (100 + dom * 8 + xcd), &expected, cu + 1, __ATOMIC_RELAXED,
        __ATOMIC_RELAXED, __HIP_MEMORY_SCOPE_AGENT);
  }
  __syncthreads();

  int* prog0  = bar + 16 * 132;
  int* prog1  = bar + 16 * 133;
  int* progB0 = bar + 16 * 134;
  int* progB1 = bar + 16 * 135;

  // ---- startup gates ----
  if (tid == 0) {
    int guard = 0;
    if (dom == 0) {
      while (__hip_atomic_load(progB0, __ATOMIC_RELAXED, __HIP_MEMORY_SCOPE_AGENT) < 1) {
        __builtin_amdgcn_s_sleep(1); if (++guard > (1 << 22)) break;
      }
    } else if (dom == 1) {
      while (__hip_atomic_load(progB1, __ATOMIC_RELAXED, __HIP_MEMORY_SCOPE_AGENT) < 1) {
        __builtin_amdgcn_s_sleep(1); if (++guard > (1 << 22)) break;
      }
    } else if (dom == 3) {
      while (__hip_atomic_load(prog0, __ATOMIC_RELAXED, __HIP_MEMORY_SCOPE_AGENT) < 1) {
        __builtin_amdgcn_s_sleep(1); if (++guard > (1 << 22)) break;
      }
    }
  }
  __syncthreads();

  int* myleaf = bar + 16 * (dom * 8 + (cuD & 7));
  int* myroot = bar + 16 * (32 + dom);
  int* myprog = bar + 16 * (132 + dom);
  int* rel  = bar + 16 * (36 + dom * 8 + xcd);
  int* relB = bar + 16 * (68 + dom * 8 + xcd);

  if (serial) {
    // ================= SERIAL DOMAIN (Wh only) =================
    unsigned short* hr = lay ? h1r : h0r;
    unsigned short* gr = lay ? g1x : g0x;
    const int khalf = (w >> 2) & 1;       // K-half for working waves (w<8)
    const int ktb = khalf * 16;
    const int bt = w & 3;
    const int bg = bt * 16 + bl;
    const int mloc = cuD * 16 + q * 4;    // lane's first m
    const bool work = (w < 8);
    const bool ownerS = (w < 4);
    float c_st[4] = {0.f, 0.f, 0.f, 0.f};
    if (ownerS) {
#pragma unroll
      for (int e = 0; e < 4; ++e)
        c_st[e] = c_in[lay * BM + bg * M_SZ + mloc + e];
    }

    for (int k = 0; k < T_STEPS; ++k) {
      const int rs = (k + RING - 1) & (RING - 1);
      const int wsl = k & (RING - 1);
      f32x4 a0 = {0.f,0.f,0.f,0.f}, a1 = {0.f,0.f,0.f,0.f};
      f32x4 a2 = {0.f,0.f,0.f,0.f}, a3 = {0.f,0.f,0.f,0.f};
      unsigned long long gv0 = 0, gv1 = 0, gv2 = 0, gv3 = 0;
      if (work) {
        const unsigned short* hp = hr + (size_t)rs * BM + (size_t)bg * M_SZ;
        short8 f[16];
#pragma unroll
        for (int j = 0; j < 16; ++j) f[j] = ld16(hp + (ktb + j) * 32 + ko);
        if (ownerS) {   // gates loads fly alongside the h loads
          const unsigned short* gp = gr + (size_t)wsl * GSTRIDE +
                                     (size_t)bg * G4M + mloc;
          gv0 = *(const unsigned long long*)(gp);
          gv1 = *(const unsigned long long*)(gp + 1024);
          gv2 = *(const unsigned long long*)(gp + 2048);
          gv3 = *(const unsigned long long*)(gp + 3072);
        }
        asm volatile("" ::
          "v"(f[0]), "v"(f[1]), "v"(f[2]), "v"(f[3]), "v"(f[4]), "v"(f[5]),
          "v"(f[6]), "v"(f[7]), "v"(f[8]), "v"(f[9]), "v"(f[10]), "v"(f[11]),
          "v"(f[12]), "v"(f[13]), "v"(f[14]), "v"(f[15]));
        __builtin_amdgcn_sched_barrier(0);
#pragma unroll
        for (int j = 0; j < 16; ++j) {
          int kt = ktb + j;
          a0 = __builtin_amdgcn_mfma_f32_16x16x32_bf16(sW[0][kt][lane], f[j], a0, 0, 0, 0);
          a1 = __builtin_amdgcn_mfma_f32_16x16x32_bf16(sW[1][kt][lane], f[j], a1, 0, 0, 0);
          a2 = __builtin_amdgcn_mfma_f32_16x16x32_bf16(sW[2][kt][lane], f[j], a2, 0, 0, 0);
          a3 = __builtin_amdgcn_mfma_f32_16x16x32_bf16(sW[3][kt][lane], f[j], a3, 0, 0, 0);
        }
      }
      if (work && !ownerS) {
        redS[0][bt][lane] = a0; redS[1][bt][lane] = a1;
        redS[2][bt][lane] = a2; redS[3][bt][lane] = a3;
      }
      asm volatile("s_waitcnt lgkmcnt(0)" ::: "memory");
      __builtin_amdgcn_s_barrier();
      __builtin_amdgcn_sched_barrier(0);
      if (ownerS) {
        f32x4 t0 = a0 + redS[0][bt][lane];
        f32x4 t1 = a1 + redS[1][bt][lane];
        f32x4 t2 = a2 + redS[2][bt][lane];
        f32x4 t3 = a3 + redS[3][bt][lane];
        float hv[4];
#pragma unroll
        for (int e = 0; e < 4; ++e) {
          float ig = t0[e] + bf2f((unsigned int)(gv0 >> (16 * e)));
          float fg = t1[e] + bf2f((unsigned int)(gv1 >> (16 * e)));
          float gg = t2[e] + bf2f((unsigned int)(gv2 >> (16 * e)));
          float og = t3[e] + bf2f((unsigned int)(gv3 >> (16 * e)));
          float c = sigf(fg) * c_st[e] + sigf(ig) * tanhfast(gg);
          c_st[e] = c;
          hv[e] = sigf(og) * tanhfast(c);
        }
        // h store FIRST (must be visible at arrival); out/finals after.
        unsigned long long hb =
            (unsigned long long)f2bf(hv[0]) |
            ((unsigned long long)f2bf(hv[1]) << 16) |
            ((unsigned long long)f2bf(hv[2]) << 32) |
            ((unsigned long long)f2bf(hv[3]) << 48);
        __hip_atomic_store(
            (unsigned long long*)(hr + (size_t)wsl * BM + (size_t)bg * M_SZ + mloc),
            hb, __ATOMIC_RELAXED, __HIP_MEMORY_SCOPE_AGENT);
        if (lay == 1) {
          f32x4 ov = { hv[0], hv[1], hv[2], hv[3] };
          store_wt16(out + ((size_t)bg * T_STEPS + k) * M_SZ + mloc, ov);
        }
        if (k == T_STEPS - 1) {
          f32x4 hf = { hv[0], hv[1], hv[2], hv[3] };
          f32x4 cf = { c_st[0], c_st[1], c_st[2], c_st[3] };
          store_wt16(out + OUTS + (size_t)lay * BM + (size_t)bg * M_SZ + mloc, hf);
          store_wt16(out + OUTS + 2 * (size_t)BM + (size_t)lay * BM +
                     (size_t)bg * M_SZ + mloc, cf);
        }
        // L0: full drain (h consumed by B1 each step, incl. k=255).
        // L1: vmcnt(1) — in-order retirement => h retired; out/finals fly
        //     (no on-device consumer; kernel-boundary fence flushes them).
        if (lay == 0)
          asm volatile("s_waitcnt vmcnt(0)" ::: "memory");
        else
          asm volatile("s_waitcnt vmcnt(1)" ::: "memory");
      }
      __builtin_amdgcn_s_barrier();
      if (tid == 0) {
        const int target = k + 1;
        int prev = __hip_atomic_fetch_add(myleaf, 1, __ATOMIC_RELAXED, __HIP_MEMORY_SCOPE_AGENT);
        if ((prev & 7) == 7) {
          int pr2 = __hip_atomic_fetch_add(myroot, 1, __ATOMIC_RELAXED, __HIP_MEMORY_SCOPE_AGENT);
          if ((pr2 & 7) == 7) {
            __hip_atomic_store(myprog, target, __ATOMIC_RELAXED, __HIP_MEMORY_SCOPE_AGENT);
#pragma unroll
            for (int xx = 0; xx < 8; ++xx)
              __hip_atomic_store(bar + 16 * (36 + dom * 8 + xx), target,
                                 __ATOMIC_RELAXED, __HIP_MEMORY_SCOPE_AGENT);
          }
        }
        int guard = 0;
        while (__hip_atomic_load(rel, __ATOMIC_RELAXED, __HIP_MEMORY_SCOPE_AGENT) < target) {
          __builtin_amdgcn_s_sleep(1);
          if (++guard > (1 << 22)) break;
        }
        if (k + 1 < T_STEPS) {
          int* need_p = (dom == 0) ? progB0 : progB1;
          guard = 0;
          while (__hip_atomic_load(need_p, __ATOMIC_RELAXED, __HIP_MEMORY_SCOPE_AGENT) < k + 2) {
            __builtin_amdgcn_s_sleep(1);
            if (++guard > (1 << 22)) break;
          }
          if (dom == 0 && k + 1 >= RING) {
            guard = 0;
            while (__hip_atomic_load(progB1, __ATOMIC_RELAXED, __HIP_MEMORY_SCOPE_AGENT) < k - 30) {
              __builtin_amdgcn_s_sleep(1);
              if (++guard > (1 << 22)) break;
            }
          }
        }
        if ((k & (RING - 1)) == (RING - 1)) {
          if (leader) {
            asm volatile("buffer_inv sc0 sc1\n\ts_waitcnt vmcnt(0)" ::: "memory");
            __hip_atomic_store(relB, target, __ATOMIC_RELAXED, __HIP_MEMORY_SCOPE_AGENT);
          } else {
            guard = 0;
            while (__hip_atomic_load(relB, __ATOMIC_RELAXED, __HIP_MEMORY_SCOPE_AGENT) < target) {
              __builtin_amdgcn_s_sleep(1);
              if (++guard > (1 << 22)) break;
            }
            asm volatile("buffer_inv sc0\n\ts_waitcnt vmcnt(0)" ::: "memory");
          }
        }
      }
      __builtin_amdgcn_s_barrier();
      __builtin_amdgcn_sched_barrier(0);
    }
  } else {
    // ================= BRIDGE DOMAIN (Wx only; K-split waves) =================
    unsigned short* gr = lay ? g1x : g0x;
    const int khB = w >> 3;             // K-half
    const int rg = (w >> 2) & 1;        // rt pair: rt = rg*2, rg*2+1
    const int bt = w & 3;
    const int bg = bt * 16 + bl;
    const int ktbB = khB * 16;
    const int rt0 = rg * 2, rt1 = rg * 2 + 1;
    const int row0 = cuD * 64 + rt0 * 16 + q * 4;
    const int row1 = cuD * 64 + rt1 * 16 + q * 4;
    float bs0[4], bs1[4];
#pragma unroll
    for (int e = 0; e < 4; ++e) {
      bs0[e] = bias[lay * G4M + row0 + e];
      bs1[e] = bias[lay * G4M + row1 + e];
    }

    for (int k = 0; k < T_STEPS; ++k) {
      const int wsl = k & (RING - 1);
      const unsigned short* ip =
          lay ? (h0r + (size_t)wsl * BM + (size_t)bg * M_SZ)     // h0[t=k]
              : (xb + ((size_t)bg * T_STEPS + k) * N_SZ);        // x[t=k]
      f32x4 acc0 = {0.f,0.f,0.f,0.f}, acc1 = {0.f,0.f,0.f,0.f};
      if (khB == 0) {
#pragma unroll
        for (int e = 0; e < 4; ++e) { acc0[e] = bs0[e]; acc1[e] = bs1[e]; }
      }
      short8 f[16];
#pragma unroll
      for (int j = 0; j < 16; ++j) f[j] = ld16(ip + (ktbB + j) * 32 + ko);
      asm volatile("" ::
        "v"(f[0]), "v"(f[1]), "v"(f[2]), "v"(f[3]), "v"(f[4]), "v"(f[5]),
        "v"(f[6]), "v"(f[7]), "v"(f[8]), "v"(f[9]), "v"(f[10]), "v"(f[11]),
        "v"(f[12]), "v"(f[13]), "v"(f[14]), "v"(f[15]));
      __builtin_amdgcn_sched_barrier(0);
#pragma unroll
      for (int j = 0; j < 16; ++j) {
        int kt = ktbB + j;
        acc0 = __builtin_amdgcn_mfma_f32_16x16x32_bf16(sW[rt0][kt][lane], f[j], acc0, 0, 0, 0);
        acc1 = __builtin_amdgcn_mfma_f32_16x16x32_bf16(sW[rt1][kt][lane], f[j], acc1, 0, 0, 0);
      }
      if (khB == 1) {
        redS[rt0][bt][lane] = acc0;
        redS[rt1][bt][lane] = acc1;
      }
      asm volatile("s_waitcnt lgkmcnt(0)" ::: "memory");
      __builtin_amdgcn_s_barrier();
      __builtin_amdgcn_sched_barrier(0);
      if (khB == 0) {
        f32x4 t0 = acc0 + redS[rt0][bt][lane];
        f32x4 t1 = acc1 + redS[rt1][bt][lane];
        unsigned long long gb0 =
            (unsigned long long)f2bf(t0[0]) |
            ((unsigned long long)f2bf(t0[1]) << 16) |
            ((unsigned long long)f2bf(t0[2]) << 32) |
            ((unsigned long long)f2bf(t0[3]) << 48);
        unsigned long long gb1 =
            (unsigned long long)f2bf(t1[0]) |
            ((unsigned long long)f2bf(t1[1]) << 16) |
            ((unsigned long long)f2bf(t1[2]) << 32) |
            ((unsigned long long)f2bf(t1[3]) << 48);
        unsigned short* gbse = gr + (size_t)wsl * GSTRIDE + (size_t)bg * G4M;
        __hip_atomic_store((unsigned long long*)(gbse + row0), gb0,
                           __ATOMIC_RELAXED, __HIP_MEMORY_SCOPE_AGENT);
        __hip_atomic_store((unsigned long long*)(gbse + row1), gb1,
                           __ATOMIC_RELAXED, __HIP_MEMORY_SCOPE_AGENT);
        asm volatile("s_waitcnt vmcnt(0)" ::: "memory");
      }
      __builtin_amdgcn_s_barrier();
      if (tid == 0) {
        const int target = k + 1;
        int prev = __hip_atomic_fetch_add(myleaf, 1, __ATOMIC_RELAXED, __HIP_MEMORY_SCOPE_AGENT);
        if ((prev & 7) == 7) {
          int pr2 = __hip_atomic_fetch_add(myroot, 1, __ATOMIC_RELAXED, __HIP_MEMORY_SCOPE_AGENT);
          if ((pr2 & 7) == 7) {
            __hip_atomic_store(myprog, target, __ATOMIC_RELAXED, __HIP_MEMORY_SCOPE_AGENT);
#pragma unroll
            for (int xx = 0; xx < 8; ++xx)
              __hip_atomic_store(bar + 16 * (36 + dom * 8 + xx), target,
                                 __ATOMIC_RELAXED, __HIP_MEMORY_SCOPE_AGENT);
          }
        }
        int guard = 0;
        while (__hip_atomic_load(rel, __ATOMIC_RELAXED, __HIP_MEMORY_SCOPE_AGENT) < target) {
          __builtin_amdgcn_s_sleep(1);
          if (++guard > (1 << 22)) break;
        }
        if (dom == 3 && k + 1 < T_STEPS) {      // need h0[k+1]
          guard = 0;
          while (__hip_atomic_load(prog0, __ATOMIC_RELAXED, __HIP_MEMORY_SCOPE_AGENT) < k + 2) {
            __builtin_amdgcn_s_sleep(1);
            if (++guard > (1 << 22)) break;
          }
        }
        if (k + 1 >= RING && k + 1 < T_STEPS) { // own gates-ring reuse
          int* cons = (dom == 2) ? prog0 : prog1;
          guard = 0;
          while (__hip_atomic_load(cons, __ATOMIC_RELAXED, __HIP_MEMORY_SCOPE_AGENT) < k - 30) {
            __builtin_amdgcn_s_sleep(1);
            if (++guard > (1 << 22)) break;
          }
        }
        if ((k & (RING - 1)) == (RING - 1)) {
          if (leader) {
            asm volatile("buffer_inv sc0 sc1\n\ts_waitcnt vmcnt(0)" ::: "memory");
            __hip_atomic_store(relB, target, __ATOMIC_RELAXED, __HIP_MEMORY_SCOPE_AGENT);
          } else {
            guard = 0;
            while (__hip_atomic_load(relB, __ATOMIC_RELAXED, __HIP_MEMORY_SCOPE_AGENT) < target) {
              __builtin_amdgcn_s_sleep(1);
              if (++guard > (1 << 22)) break;
            }
            asm volatile("buffer_inv sc0\n\ts_waitcnt vmcnt(0)" ::: "memory");
          }
        }
      }
      __builtin_amdgcn_s_barrier();
      __builtin_amdgcn_sched_barrier(0);
    }
  }
}

extern "C" void kernel_launch(void* const* d_in, const int* in_sizes, int n_in,
                              void* d_out, int out_size, void* d_ws, size_t ws_size,
                              hipStream_t stream) {
  (void)in_sizes; (void)n_in; (void)out_size; (void)ws_size;
  const float* x  = (const float*)d_in[0];
  const float* h  = (const float*)d_in[1];
  const float* c  = (const float*)d_in[2];
  const float* Wx = (const float*)d_in[3];
  const float* Wh = (const float*)d_in[4];
  const float* b  = (const float*)d_in[5];
  float* out = (float*)d_out;

  char* ws = (char*)d_ws;
  int* bar = (int*)ws;                                       // 16 KB counters
  unsigned short* h0r = (unsigned short*)(ws + 16384);
  unsigned short* h1r = (unsigned short*)(ws + 16384 + (size_t)RING * BM * 2);
  unsigned short* g0x = (unsigned short*)(ws + 16384 + (size_t)RING * BM * 4);
  unsigned short* g1x = (unsigned short*)(ws + 16384 + (size_t)RING * BM * 4 +
                                          (size_t)RING * GSTRIDE * 2);
  unsigned short* xb  = (unsigned short*)(ws + 16384 + (size_t)RING * BM * 4 +
                                          (size_t)RING * GSTRIDE * 4);
  // ws use: 16 KB + 8 MB (h rings) + 32 MB (gates rings) + 32 MB (x) ~= 72 MB

  (void)hipMemsetAsync(ws, 0, 16384, stream);
  convert_x_kernel<<<2048, 256, 0, stream>>>(x, xb, (B_SZ * T_STEPS * N_SZ) / 4);
  init_h_kernel<<<256, 256, 0, stream>>>(h, h0r, h1r);
  lstm_pipeline<<<256, 1024, 0, stream>>>(xb, c, Wx, Wh, b, out,
                                          h0r, h1r, g0x, g1x, bar);
}